// Round 13
// baseline (3285.632 us; speedup 1.0000x reference)
//
#include <hip/hip_runtime.h>
#include <stdint.h>

#define H_ 64
#define W_ 64
#define D_ 256
#define U_ 512
#define KREC 1024           // 512 (h_up, w0) + 512 (h_left, w1)
#define CELL_ELT (32 * U_)  // elements per cell in hgrid

typedef __attribute__((ext_vector_type(8))) _Float16 half8;
typedef __attribute__((ext_vector_type(8))) unsigned short ushort8;
typedef __attribute__((ext_vector_type(4))) float f32x4;

__device__ __forceinline__ unsigned short f2h(float f) {
    _Float16 h = (_Float16)f;  // RNE
    return __builtin_bit_cast(unsigned short, h);
}

// Bank-conflict-free LDS offset: fold byte-addr bits [9:7] and row into bits [6:4].
// Involution per (row, o>>7): apply the SAME function on write and read.
__device__ __forceinline__ int swzo(int r, int o) {
    return o ^ (((r ^ (o >> 7)) & 7) << 4);
}

// wcT2[n][k] fp16: [w0; w1] transposed. n in [0,512), k in [0,1024).
__global__ void prep_w(const float* __restrict__ w0,
                       const float* __restrict__ w1,
                       unsigned short* __restrict__ wcT2) {
    int n = blockIdx.x;
    for (int k = threadIdx.x; k < KREC; k += blockDim.x) {
        float v = (k < U_) ? w0[(size_t)k * U_ + n] : w1[(size_t)(k - U_) * U_ + n];
        wcT2[(size_t)n * KREC + k] = f2h(v);
    }
}

// waxT[n][k] fp16, n in [0,512), k in [0,256)
__global__ void prep_waxT(const float* __restrict__ wax,
                          unsigned short* __restrict__ waxT) {
    int n = blockIdx.x;
    for (int k = threadIdx.x; k < D_; k += blockDim.x)
        waxT[(size_t)n * D_ + k] = f2h(wax[(size_t)k * U_ + n]);
}

// Z = x@wax + ba per cell, stored FRAGMENT-ORDERED fp32:
// zfb[cell][g 16][lane 64][16]; value idx = mt*8 + ntp*4 + rr maps to
// (row = mt*16 + (lane>>4)*4 + rr, col = g*32 + ntp*16 + (lane&15)).
__global__ __launch_bounds__(256) void prep_z(
    const float* __restrict__ x,
    const unsigned short* __restrict__ waxT,
    const float* __restrict__ ba,
    float* __restrict__ zfb)
{
    __shared__ char xs[32 * 512];  // 16KB fp16, swizzled
    const int cell = blockIdx.x;
    const int t = threadIdx.x, lane = t & 63, wv = t >> 6;
    const int l15 = lane & 15, lh = lane >> 4;
    const int r = t >> 3, c8 = t & 7;

    {
        const float4* src = reinterpret_cast<const float4*>(
            x + (size_t)r * (H_ * W_ * D_) + (size_t)cell * D_ + c8 * 32);
        float4 f[8];
        #pragma unroll
        for (int q = 0; q < 8; ++q) f[q] = src[q];
        #pragma unroll
        for (int s = 0; s < 4; ++s) {
            float4 a = f[2 * s], b = f[2 * s + 1];
            ushort8 o;
            o[0] = f2h(a.x); o[1] = f2h(a.y); o[2] = f2h(a.z); o[3] = f2h(a.w);
            o[4] = f2h(b.x); o[5] = f2h(b.y); o[6] = f2h(b.z); o[7] = f2h(b.w);
            int ob = c8 * 64 + s * 16;
            *reinterpret_cast<ushort8*>(xs + r * 512 + swzo(r, ob)) = o;
        }
    }
    __syncthreads();

    f32x4 zero = {0.f, 0.f, 0.f, 0.f};
    f32x4 acc[2][8];
    #pragma unroll
    for (int m = 0; m < 2; ++m)
        #pragma unroll
        for (int n = 0; n < 8; ++n) acc[m][n] = zero;

    const char* ar0 = xs + l15 * 512;
    const char* ar1 = xs + (16 + l15) * 512;
    #pragma unroll
    for (int ks = 0; ks < 8; ++ks) {
        int ob = ks * 64 + lh * 16;
        int oo = swzo(l15, ob);
        half8 af0 = *reinterpret_cast<const half8*>(ar0 + oo);
        half8 af1 = *reinterpret_cast<const half8*>(ar1 + oo);
        #pragma unroll
        for (int ntg = 0; ntg < 8; ++ntg) {
            int col = wv * 128 + ntg * 16 + l15;
            half8 bf = *reinterpret_cast<const half8*>(waxT + (size_t)col * D_ + ks * 32 + lh * 8);
            acc[0][ntg] = __builtin_amdgcn_mfma_f32_16x16x32_f16(af0, bf, acc[0][ntg], 0, 0, 0);
            acc[1][ntg] = __builtin_amdgcn_mfma_f32_16x16x32_f16(af1, bf, acc[1][ntg], 0, 0, 0);
        }
    }

    #pragma unroll
    for (int s = 0; s < 4; ++s) {
        float* dst = zfb + (((size_t)cell * 16 + wv * 4 + s) * 64 + lane) * 16;
        #pragma unroll
        for (int mt = 0; mt < 2; ++mt)
            #pragma unroll
            for (int ntp = 0; ntp < 2; ++ntp) {
                float bav = ba[wv * 128 + s * 32 + ntp * 16 + l15];
                f32x4 o;
                o[0] = acc[mt][s * 2 + ntp][0] + bav;
                o[1] = acc[mt][s * 2 + ntp][1] + bav;
                o[2] = acc[mt][s * 2 + ntp][2] + bav;
                o[3] = acc[mt][s * 2 + ntp][3] + bav;
                *reinterpret_cast<f32x4*>(dst + mt * 8 + ntp * 4) = o;
            }
    }
}

// Fused-column persistent recurrence: block j = entire column j (1024 thr, 16 waves).
// Up-dependency is block-local (LDS ping-pong); only left crosses blocks (1 producer).
// flags[cell] = 1 when cell is published. hgrid carries the SWIZZLED cell image.
__global__ __launch_bounds__(1024, 1) void mdrnn_col(
    const unsigned short* __restrict__ wcT2,
    const float* __restrict__ zfb,
    unsigned short* __restrict__ hgrid,
    int* flags,
    float* __restrict__ out)
{
    __shared__ char hbuf0[32 * 1024];  // cell h, even rows' output (swizzled [32][512] fp16)
    __shared__ char hbuf1[32 * 1024];  // cell h, odd rows' output
    __shared__ char hleft[32 * 1024];  // staged left-cell image

    const int j = (int)blockIdx.x;
    const int t = threadIdx.x, lane = t & 63, wv = t >> 6;  // wv 0..15
    const int l15 = lane & 15, lh = lane >> 4;

    // recurrent weights: wave wv covers cols wv*32 + nt*16 + l15, K 0..1023 (256 VGPR)
    half8 breg[2][32];
    {
        const unsigned short* wb = wcT2 + (size_t)(wv * 32 + l15) * KREC + lh * 8;
        #pragma unroll
        for (int nt = 0; nt < 2; ++nt)
            #pragma unroll
            for (int ks = 0; ks < 32; ++ks)
                breg[nt][ks] = *reinterpret_cast<const half8*>(wb + (size_t)nt * 16 * KREC + ks * 32);
    }

    #pragma clang loop unroll(disable)
    for (int i = 0; i < H_; ++i) {
        const int cell = i * W_ + j;
        char* hcur  = (i & 1) ? hbuf1 : hbuf0;
        const char* hprev = (i & 1) ? hbuf0 : hbuf1;

        // Z prefetch (plain loads; land under MFMA/poll)
        const f32x4* zp = reinterpret_cast<const f32x4*>(
            zfb + (((size_t)cell * 16 + wv) * 64 + lane) * 16);
        f32x4 z0 = zp[0], z1 = zp[1], z2 = zp[2], z3 = zp[3];

        f32x4 zero = {0.f, 0.f, 0.f, 0.f};
        f32x4 acc00 = zero, acc01 = zero, acc10 = zero, acc11 = zero;

#define MSTEP(base, kk, kb)                                                                      \
        {                                                                                        \
            int ob = (kk) * 64 + lh * 16;                                                        \
            int oo = swzo(l15, ob); /* (16+l15)&7 == l15&7: same fold both rows */               \
            half8 af0 = *reinterpret_cast<const half8*>((base) + l15 * 1024 + oo);               \
            half8 af1 = *reinterpret_cast<const half8*>((base) + (16 + l15) * 1024 + oo);        \
            acc00 = __builtin_amdgcn_mfma_f32_16x16x32_f16(af0, breg[0][(kb)], acc00, 0, 0, 0);  \
            acc01 = __builtin_amdgcn_mfma_f32_16x16x32_f16(af0, breg[1][(kb)], acc01, 0, 0, 0);  \
            acc10 = __builtin_amdgcn_mfma_f32_16x16x32_f16(af1, breg[0][(kb)], acc10, 0, 0, 0);  \
            acc11 = __builtin_amdgcn_mfma_f32_16x16x32_f16(af1, breg[1][(kb)], acc11, 0, 0, 0);  \
        }

        // 1. UP half: block-local, no wait (reads hprev; K 0..511 = w0)
        if (i > 0) {
            #pragma unroll
            for (int ks = 0; ks < 16; ++ks) MSTEP(hprev, ks, ks)
        }

        // 2. LEFT: poll single producer's flag, then stage 32KB (plain 16B loads)
        if (j > 0) {
            const int* fl = flags + (cell - 1);
            while (__hip_atomic_load(fl, __ATOMIC_RELAXED, __HIP_MEMORY_SCOPE_AGENT) == 0)
                __builtin_amdgcn_s_sleep(1);
            asm volatile("" ::: "memory");  // no staging-load hoisting above the poll
            const ushort8* gl = reinterpret_cast<const ushort8*>(
                hgrid + (size_t)(cell - 1) * CELL_ELT);
            ushort8 v0 = gl[t * 2], v1 = gl[t * 2 + 1];
            *reinterpret_cast<ushort8*>(hleft + t * 32)      = v0;  // linear copy:
            *reinterpret_cast<ushort8*>(hleft + t * 32 + 16) = v1;  // image already swizzled
        }
        __syncthreads();  // B_stage

        // 3. LEFT half MFMA (K 512..1023 = w1; local k index kk = ks-16)
        if (j > 0) {
            #pragma unroll
            for (int ks = 16; ks < 32; ++ks) MSTEP(hleft, ks - 16, ks)
        }
#undef MSTEP

        // 4. epilogue p1: acc + Z, tanh -> hcur (swizzled [32][512] fp16); out direct
        const bool lastcell = (i == H_ - 1) && (j == W_ - 1);
        const int col0 = wv * 32 + l15;
        #pragma unroll
        for (int mt = 0; mt < 2; ++mt) {
            f32x4 a0 = mt ? acc10 : acc00;
            f32x4 a1 = mt ? acc11 : acc01;
            f32x4 zq0 = mt ? z2 : z0;
            f32x4 zq1 = mt ? z3 : z1;
            #pragma unroll
            for (int rr = 0; rr < 4; ++rr) {
                int row = mt * 16 + lh * 4 + rr;  // C/D: row=(lane>>4)*4+reg
                float v0 = fminf(fmaxf(a0[rr] + zq0[rr], -15.f), 15.f);
                float v1 = fminf(fmaxf(a1[rr] + zq1[rr], -15.f), 15.f);
                float e0 = __expf(2.f * v0), e1 = __expf(2.f * v1);
                float th0 = (e0 - 1.f) / (e0 + 1.f);
                float th1 = (e1 - 1.f) / (e1 + 1.f);
                *reinterpret_cast<unsigned short*>(
                    hcur + row * 1024 + swzo(row, col0 * 2))      = f2h(th0);
                *reinterpret_cast<unsigned short*>(
                    hcur + row * 1024 + swzo(row, col0 * 2 + 32)) = f2h(th1);
                if (lastcell) {
                    out[(size_t)row * U_ + col0]      = th0;
                    out[(size_t)row * U_ + col0 + 16] = th1;
                }
            }
        }
        __syncthreads();  // B_t: hcur complete (also: hleft reads done before next staging)

        // 5. publish: linear copy of swizzled image -> global (4x8B agent stores/thread)
        {
            const unsigned long long* sq = reinterpret_cast<const unsigned long long*>(hcur + t * 32);
            unsigned long long* gq = reinterpret_cast<unsigned long long*>(
                hgrid + (size_t)cell * CELL_ELT) + (size_t)t * 4;
            #pragma unroll
            for (int q = 0; q < 4; ++q)
                __hip_atomic_store(gq + q, sq[q], __ATOMIC_RELAXED, __HIP_MEMORY_SCOPE_AGENT);
        }
        asm volatile("s_waitcnt vmcnt(0)" ::: "memory");  // all stores acked at LLC
        __syncthreads();  // B_flag: every thread's stores drained
        if (t == 0)
            __hip_atomic_store(&flags[cell], 1, __ATOMIC_RELAXED, __HIP_MEMORY_SCOPE_AGENT);
    }
}

extern "C" void kernel_launch(void* const* d_in, const int* in_sizes, int n_in,
                              void* d_out, int out_size, void* d_ws, size_t ws_size,
                              hipStream_t stream) {
    const float* x   = (const float*)d_in[0];
    const float* wax = (const float*)d_in[1];
    const float* w0  = (const float*)d_in[2];
    const float* w1  = (const float*)d_in[3];
    const float* ba  = (const float*)d_in[4];
    float* out = (float*)d_out;

    // ws layout (total ~386 MiB; observed ws >= 512 MiB):
    // wcT2 1MiB | waxT 256KiB | flags 16KiB | (pad to 2MiB) zfb 256MiB | hgrid 128MiB
    char* w = (char*)d_ws;
    unsigned short* wcT2  = (unsigned short*)(w);
    unsigned short* waxT  = (unsigned short*)(w + (1u << 20));
    int*            flags = (int*)(w + (1u << 20) + (256u << 10));
    float*          zfb   = (float*)(w + (2u << 20));
    unsigned short* hgrid = (unsigned short*)(w + (2u << 20) + ((size_t)256 << 20));

    (void)hipMemsetAsync(flags, 0, (size_t)H_ * W_ * sizeof(int), stream);
    prep_w   <<<dim3(U_), dim3(256), 0, stream>>>(w0, w1, wcT2);
    prep_waxT<<<dim3(U_), dim3(256), 0, stream>>>(wax, waxT);
    prep_z   <<<dim3(H_ * W_), dim3(256), 0, stream>>>(x, waxT, ba, zfb);
    // 64 blocks (1 column each), 1024 threads, 96KB LDS -> trivially co-resident
    mdrnn_col<<<dim3(W_), dim3(1024), 0, stream>>>(wcT2, zfb, hgrid, flags, out);
}

// Round 14
// 995.952 us; speedup vs baseline: 3.2990x; 3.2990x over previous
//
#include <hip/hip_runtime.h>
#include <stdint.h>

#define H_ 64
#define W_ 64
#define D_ 256
#define U_ 512
#define KREC 1024           // 512 (h_up, w0) + 512 (h_left, w1)
#define CELL_ELT (32 * U_)  // elements per cell in hgrid

typedef __attribute__((ext_vector_type(8))) _Float16 half8;
typedef __attribute__((ext_vector_type(8))) unsigned short ushort8;
typedef __attribute__((ext_vector_type(4))) float f32x4;

__device__ __forceinline__ unsigned short f2h(float f) {
    _Float16 h = (_Float16)f;  // RNE
    return __builtin_bit_cast(unsigned short, h);
}

// Bank-conflict-free LDS offset: fold byte-addr bits [9:7] and row into bits [6:4].
__device__ __forceinline__ int swzo(int r, int o) {
    return o ^ (((r ^ (o >> 7)) & 7) << 4);
}

// wcT2[n][k] fp16: [w0; w1] transposed. n in [0,512), k in [0,1024).
__global__ void prep_w(const float* __restrict__ w0,
                       const float* __restrict__ w1,
                       unsigned short* __restrict__ wcT2) {
    int n = blockIdx.x;
    for (int k = threadIdx.x; k < KREC; k += blockDim.x) {
        float v = (k < U_) ? w0[(size_t)k * U_ + n] : w1[(size_t)(k - U_) * U_ + n];
        wcT2[(size_t)n * KREC + k] = f2h(v);
    }
}

// waxT[n][k] fp16, n in [0,512), k in [0,256)
__global__ void prep_waxT(const float* __restrict__ wax,
                          unsigned short* __restrict__ waxT) {
    int n = blockIdx.x;
    for (int k = threadIdx.x; k < D_; k += blockDim.x)
        waxT[(size_t)n * D_ + k] = f2h(wax[(size_t)k * U_ + n]);
}

// Z = x@wax + ba per cell, stored FRAGMENT-ORDERED **fp16** (halves LLC footprint):
// zfh[cell][gw 16][lane 64][16]; value idx = mt*8 + ntp*4 + rr maps to
// (row = mt*16 + (lane>>4)*4 + rr, col = gw*32 + ntp*16 + (lane&15)).
__global__ __launch_bounds__(256) void prep_z(
    const float* __restrict__ x,
    const unsigned short* __restrict__ waxT,
    const float* __restrict__ ba,
    unsigned short* __restrict__ zfh)
{
    __shared__ char xs[32 * 512];  // 16KB fp16, swizzled
    const int cell = blockIdx.x;
    const int t = threadIdx.x, lane = t & 63, wv = t >> 6;
    const int l15 = lane & 15, lh = lane >> 4;
    const int r = t >> 3, c8 = t & 7;

    {
        const float4* src = reinterpret_cast<const float4*>(
            x + (size_t)r * (H_ * W_ * D_) + (size_t)cell * D_ + c8 * 32);
        float4 f[8];
        #pragma unroll
        for (int q = 0; q < 8; ++q) f[q] = src[q];
        #pragma unroll
        for (int s = 0; s < 4; ++s) {
            float4 a = f[2 * s], b = f[2 * s + 1];
            ushort8 o;
            o[0] = f2h(a.x); o[1] = f2h(a.y); o[2] = f2h(a.z); o[3] = f2h(a.w);
            o[4] = f2h(b.x); o[5] = f2h(b.y); o[6] = f2h(b.z); o[7] = f2h(b.w);
            int ob = c8 * 64 + s * 16;
            *reinterpret_cast<ushort8*>(xs + r * 512 + swzo(r, ob)) = o;
        }
    }
    __syncthreads();

    f32x4 zero = {0.f, 0.f, 0.f, 0.f};
    f32x4 acc[2][8];
    #pragma unroll
    for (int m = 0; m < 2; ++m)
        #pragma unroll
        for (int n = 0; n < 8; ++n) acc[m][n] = zero;

    const char* ar0 = xs + l15 * 512;
    const char* ar1 = xs + (16 + l15) * 512;
    #pragma unroll
    for (int ks = 0; ks < 8; ++ks) {
        int ob = ks * 64 + lh * 16;
        int oo = swzo(l15, ob);
        half8 af0 = *reinterpret_cast<const half8*>(ar0 + oo);
        half8 af1 = *reinterpret_cast<const half8*>(ar1 + oo);
        #pragma unroll
        for (int ntg = 0; ntg < 8; ++ntg) {
            int col = wv * 128 + ntg * 16 + l15;
            half8 bf = *reinterpret_cast<const half8*>(waxT + (size_t)col * D_ + ks * 32 + lh * 8);
            acc[0][ntg] = __builtin_amdgcn_mfma_f32_16x16x32_f16(af0, bf, acc[0][ntg], 0, 0, 0);
            acc[1][ntg] = __builtin_amdgcn_mfma_f32_16x16x32_f16(af1, bf, acc[1][ntg], 0, 0, 0);
        }
    }

    // write fragment-ordered fp16 Z (+ba): 32B per lane per s-slot (2x ushort8)
    #pragma unroll
    for (int s = 0; s < 4; ++s) {
        unsigned short* dst = zfh + (((size_t)cell * 16 + wv * 4 + s) * 64 + lane) * 16;
        float bav0 = ba[wv * 128 + s * 32 + l15];
        float bav1 = ba[wv * 128 + s * 32 + 16 + l15];
        ushort8 oa, ob;
        #pragma unroll
        for (int rr = 0; rr < 4; ++rr) {
            oa[rr]     = f2h(acc[0][s * 2 + 0][rr] + bav0);  // idx 0..3  (mt0,ntp0)
            oa[4 + rr] = f2h(acc[0][s * 2 + 1][rr] + bav1);  // idx 4..7  (mt0,ntp1)
            ob[rr]     = f2h(acc[1][s * 2 + 0][rr] + bav0);  // idx 8..11 (mt1,ntp0)
            ob[4 + rr] = f2h(acc[1][s * 2 + 1][rr] + bav1);  // idx 12..15(mt1,ntp1)
        }
        *reinterpret_cast<ushort8*>(dst)     = oa;
        *reinterpret_cast<ushort8*>(dst + 8) = ob;
    }
}

// Persistent recurrence: block b -> column j = b&63, chunk nc = b>>6.
// All 4 chunks of a column share blockIdx%8 -> SAME XCD (round-robin mapping):
// sibling staging loads L2-share one LLC fetch instead of 4.
// flags2[cell*16 + nc] = 1 when chunk nc of cell is published (cell stride 64B).
__global__ __launch_bounds__(256, 1) void mdrnn_persistent(
    const unsigned short* __restrict__ wcT2,
    const unsigned short* __restrict__ zfh,
    unsigned short* __restrict__ hgrid,
    int* flags2,
    float* __restrict__ out)
{
    __shared__ char smb[32 * 2048];          // 64KB staging: 32 rows x (up | left)
    __shared__ unsigned long long heps64[32 * 32];  // 8KB epilogue transpose, LINEAR
    unsigned short* heps16 = reinterpret_cast<unsigned short*>(heps64);

    const int j  = (int)blockIdx.x & 63;   // XCD co-location: all nc of col j on XCD j%8
    const int nc = (int)blockIdx.x >> 6;
    const int t = threadIdx.x, lane = t & 63, wv = t >> 6;
    const int l15 = lane & 15, lh = lane >> 4;
    const int r = t >> 3, c8 = t & 7;
    const int gw = nc * 4 + wv;
    const unsigned long long RDY2 = 0x0000000100000001ULL;

    // recurrent weights (128 N-cols x 1024 K) in registers: 256 VGPR
    half8 breg[2][32];
    {
        const unsigned short* wb = wcT2 + (size_t)(nc * 128 + wv * 32 + l15) * KREC + lh * 8;
        #pragma unroll
        for (int nt = 0; nt < 2; ++nt)
            #pragma unroll
            for (int ks = 0; ks < 32; ++ks)
                breg[nt][ks] = *reinterpret_cast<const half8*>(wb + (size_t)nt * 16 * KREC + ks * 32);
    }

    #pragma clang loop unroll(disable)
    for (int i = 0; i < H_; ++i) {
        const int cell = i * W_ + j;

        // Z prefetch (fp16, 32B): issued before the poll, lands during the wait
        const ushort8* zp = reinterpret_cast<const ushort8*>(
            zfh + (((size_t)cell * 16 + gw) * 64 + lane) * 16);
        ushort8 zv0 = zp[0], zv1 = zp[1];

        // ALL waves poll; each proceeds straight to staging on detection.
        if (i > 0 || j > 0) {
            const unsigned long long* fu = reinterpret_cast<const unsigned long long*>(
                flags2 + (size_t)(cell - W_) * 16);
            const unsigned long long* fl = reinterpret_cast<const unsigned long long*>(
                flags2 + (size_t)(cell - 1) * 16);
            const bool nu = (i > 0), nl = (j > 0);
            for (;;) {
                bool ok = true;
                if (nu) {
                    unsigned long long a = __hip_atomic_load(fu,     __ATOMIC_RELAXED, __HIP_MEMORY_SCOPE_AGENT);
                    unsigned long long b = __hip_atomic_load(fu + 1, __ATOMIC_RELAXED, __HIP_MEMORY_SCOPE_AGENT);
                    ok = ok && (a == RDY2) && (b == RDY2);
                }
                if (nl) {
                    unsigned long long a = __hip_atomic_load(fl,     __ATOMIC_RELAXED, __HIP_MEMORY_SCOPE_AGENT);
                    unsigned long long b = __hip_atomic_load(fl + 1, __ATOMIC_RELAXED, __HIP_MEMORY_SCOPE_AGENT);
                    ok = ok && (a == RDY2) && (b == RDY2);
                }
                if (ok) break;
                __builtin_amdgcn_s_sleep(1);
            }
        }
        asm volatile("" ::: "memory");  // no staging-load hoisting above the poll

        // single-shot staging: both frontiers -> LDS (plain cacheable loads;
        // first sibling on the XCD fills L2, the other three hit L2)
        if (i > 0) {
            const ushort8* us = reinterpret_cast<const ushort8*>(
                hgrid + (size_t)(cell - W_) * CELL_ELT + (size_t)r * U_ + c8 * 64);
            ushort8 ub[8];
            #pragma unroll
            for (int s = 0; s < 8; ++s) ub[s] = us[s];
            #pragma unroll
            for (int s = 0; s < 8; ++s) {
                int ob = c8 * 128 + s * 16;
                *reinterpret_cast<ushort8*>(smb + r * 2048 + swzo(r, ob)) = ub[s];
            }
        }
        if (j > 0) {
            const ushort8* ls = reinterpret_cast<const ushort8*>(
                hgrid + (size_t)(cell - 1) * CELL_ELT + (size_t)r * U_ + c8 * 64);
            ushort8 lb[8];
            #pragma unroll
            for (int s = 0; s < 8; ++s) lb[s] = ls[s];
            #pragma unroll
            for (int s = 0; s < 8; ++s) {
                int ob = 1024 + c8 * 128 + s * 16;
                *reinterpret_cast<ushort8*>(smb + r * 2048 + swzo(r, ob)) = lb[s];
            }
        }
        __syncthreads();  // B_stage: staging complete before fragment reads

        f32x4 zero = {0.f, 0.f, 0.f, 0.f};
        f32x4 acc00 = zero, acc01 = zero, acc10 = zero, acc11 = zero;
        const char* ar0 = smb + l15 * 2048;
        const char* ar1 = smb + (16 + l15) * 2048;

#define MSTEP(ks)                                                                                \
        {                                                                                        \
            int ob = (ks) * 64 + lh * 16;                                                        \
            int oo = swzo(l15, ob);                                                              \
            half8 af0 = *reinterpret_cast<const half8*>(ar0 + oo);                               \
            half8 af1 = *reinterpret_cast<const half8*>(ar1 + oo);                               \
            acc00 = __builtin_amdgcn_mfma_f32_16x16x32_f16(af0, breg[0][(ks)], acc00, 0, 0, 0);  \
            acc01 = __builtin_amdgcn_mfma_f32_16x16x32_f16(af0, breg[1][(ks)], acc01, 0, 0, 0);  \
            acc10 = __builtin_amdgcn_mfma_f32_16x16x32_f16(af1, breg[0][(ks)], acc10, 0, 0, 0);  \
            acc11 = __builtin_amdgcn_mfma_f32_16x16x32_f16(af1, breg[1][(ks)], acc11, 0, 0, 0);  \
        }
        if (i > 0) {
            #pragma unroll
            for (int ks = 0; ks < 16; ++ks) MSTEP(ks)
        }
        if (j > 0) {
            #pragma unroll
            for (int ks = 16; ks < 32; ++ks) MSTEP(ks)
        }
#undef MSTEP

        // epilogue phase 1: acc + Z(fp16->f32), tanh -> heps16 (LINEAR [32][128])
        const bool lastcell = (i == H_ - 1) && (j == W_ - 1);
        const int col0 = nc * 128 + wv * 32 + l15;
        const half8 hz0 = __builtin_bit_cast(half8, zv0);  // mt=0: idx0..3=ntp0, 4..7=ntp1
        const half8 hz1 = __builtin_bit_cast(half8, zv1);  // mt=1
        #pragma unroll
        for (int mt = 0; mt < 2; ++mt) {
            f32x4 a0 = mt ? acc10 : acc00;
            f32x4 a1 = mt ? acc11 : acc01;
            half8 hz = mt ? hz1 : hz0;
            #pragma unroll
            for (int rr = 0; rr < 4; ++rr) {
                int row = mt * 16 + lh * 4 + rr;  // C/D: row=(lane>>4)*4+reg
                float v0 = fminf(fmaxf(a0[rr] + (float)hz[rr],     -15.f), 15.f);
                float v1 = fminf(fmaxf(a1[rr] + (float)hz[4 + rr], -15.f), 15.f);
                float e0 = __expf(2.f * v0), e1 = __expf(2.f * v1);
                float th0 = (e0 - 1.f) / (e0 + 1.f);
                float th1 = (e1 - 1.f) / (e1 + 1.f);
                heps16[row * 128 + wv * 32 + l15]      = f2h(th0);
                heps16[row * 128 + wv * 32 + 16 + l15] = f2h(th1);
                if (lastcell) {
                    out[(size_t)row * U_ + col0]      = th0;
                    out[(size_t)row * U_ + col0 + 16] = th1;
                }
            }
        }
        __syncthreads();  // B_t: transpose complete

        // epilogue phase 2: coalesced agent-scope stores (4 x 8B per thread)
        {
            const int erow = t >> 3, e = t & 7;
            unsigned long long* gq = reinterpret_cast<unsigned long long*>(
                hgrid + (size_t)cell * CELL_ELT + (size_t)erow * U_ + nc * 128);
            #pragma unroll
            for (int q = 0; q < 4; ++q) {
                unsigned long long v = heps64[erow * 32 + q * 8 + e];
                __hip_atomic_store(gq + q * 8 + e, v, __ATOMIC_RELAXED, __HIP_MEMORY_SCOPE_AGENT);
            }
        }

        // all agent stores acked at LLC before the barrier...
        asm volatile("s_waitcnt vmcnt(0)" ::: "memory");
        __syncthreads();  // B_f: also separates this iter's LDS reads from next staging
        // ...then publish this chunk: plain agent store, no RMW
        if (t == 0)
            __hip_atomic_store(&flags2[(size_t)cell * 16 + nc], 1,
                               __ATOMIC_RELAXED, __HIP_MEMORY_SCOPE_AGENT);
    }
}

extern "C" void kernel_launch(void* const* d_in, const int* in_sizes, int n_in,
                              void* d_out, int out_size, void* d_ws, size_t ws_size,
                              hipStream_t stream) {
    const float* x   = (const float*)d_in[0];
    const float* wax = (const float*)d_in[1];
    const float* w0  = (const float*)d_in[2];
    const float* w1  = (const float*)d_in[3];
    const float* ba  = (const float*)d_in[4];
    float* out = (float*)d_out;

    // ws layout (total ~258 MiB; fits LLC working set now: zfh 128 + hgrid 128):
    // wcT2 1MiB | waxT 256KiB | flags2 256KiB | (pad to 2MiB) zfh 128MiB | hgrid 128MiB
    char* w = (char*)d_ws;
    unsigned short* wcT2   = (unsigned short*)(w);
    unsigned short* waxT   = (unsigned short*)(w + (1u << 20));
    int*            flags2 = (int*)(w + (1u << 20) + (256u << 10));
    unsigned short* zfh    = (unsigned short*)(w + (2u << 20));
    unsigned short* hgrid  = (unsigned short*)(w + (2u << 20) + ((size_t)128 << 20));

    (void)hipMemsetAsync(flags2, 0, (size_t)H_ * W_ * 16 * sizeof(int), stream);
    prep_w   <<<dim3(U_), dim3(256), 0, stream>>>(w0, w1, wcT2);
    prep_waxT<<<dim3(U_), dim3(256), 0, stream>>>(wax, waxT);
    prep_z   <<<dim3(H_ * W_), dim3(256), 0, stream>>>(x, waxT, ba, zfh);
    mdrnn_persistent<<<dim3(W_ * 4), dim3(256), 0, stream>>>(wcT2, zfh, hgrid, flags2, out);
}